// Round 7
// baseline (248.690 us; speedup 1.0000x reference)
//
#include <hip/hip_runtime.h>
#include <hip/hip_bf16.h>

// B=2, L=1024, E=512, H=8, D=64, P=64
// inputs: seq [2,1024,512], pair [2,1024,1024,64], W_qkv [512,1536],
//         W_bias [64,8], W_out [512,512], b_out [512]   (all fp32)

typedef __attribute__((ext_vector_type(8))) short bf16x8;
typedef __attribute__((ext_vector_type(4))) float f32x4;

#define BFLO(u) __uint_as_float(((unsigned)(u)) << 16)

__device__ __forceinline__ unsigned pk2(float a, float b) {
    __hip_bfloat16 ha = __float2bfloat16(a);
    __hip_bfloat16 hb = __float2bfloat16(b);
    return (unsigned)__bfloat16_as_ushort(ha) | ((unsigned)__bfloat16_as_ushort(hb) << 16);
}

// ---------------------------------------------------------------------------
// Kernel 1: QKV GEMM.  A[2048][512] @ W[512][1536] ->
//   q  bf16 [B][H][L][D] scaled by 1/8
//   k  bf16 [B][H][L][D]
//   vT bf16 [B][H][D][L]
// ---------------------------------------------------------------------------
__global__ __launch_bounds__(256, 2) void gemm_qkv_kernel(
    const float* __restrict__ A, const float* __restrict__ W,
    unsigned short* __restrict__ qbus, unsigned short* __restrict__ kbus,
    unsigned short* __restrict__ vtbus)
{
    __shared__ float smem[64 * 68];
    float* As = smem;                        // As[k][m]
    float* Bs = smem + 32 * 68;              // Bs[k][n]

    const int t  = threadIdx.x;
    const int m0 = blockIdx.y * 64;
    const int n0 = blockIdx.x * 64;
    const int tx = t & 15, ty = t >> 4;

    const int am = t >> 2, ak = (t & 3) * 8;
    const int bk = t >> 3, bn = (t & 7) * 8;

    float acc[4][4] = {};

    for (int k0 = 0; k0 < 512; k0 += 32) {
        float4 a0 = *(const float4*)&A[(size_t)(m0 + am) * 512 + k0 + ak];
        float4 a1 = *(const float4*)&A[(size_t)(m0 + am) * 512 + k0 + ak + 4];
        float4 b0 = *(const float4*)&W[(size_t)(k0 + bk) * 1536 + n0 + bn];
        float4 b1 = *(const float4*)&W[(size_t)(k0 + bk) * 1536 + n0 + bn + 4];
        __syncthreads();
        As[(ak + 0) * 68 + am] = a0.x;
        As[(ak + 1) * 68 + am] = a0.y;
        As[(ak + 2) * 68 + am] = a0.z;
        As[(ak + 3) * 68 + am] = a0.w;
        As[(ak + 4) * 68 + am] = a1.x;
        As[(ak + 5) * 68 + am] = a1.y;
        As[(ak + 6) * 68 + am] = a1.z;
        As[(ak + 7) * 68 + am] = a1.w;
        *(float4*)&Bs[bk * 68 + bn]     = b0;
        *(float4*)&Bs[bk * 68 + bn + 4] = b1;
        __syncthreads();
#pragma unroll
        for (int kk = 0; kk < 32; kk++) {
            float4 a4 = *(float4*)&As[kk * 68 + ty * 4];
            float4 b4 = *(float4*)&Bs[kk * 68 + tx * 4];
            float av[4] = {a4.x, a4.y, a4.z, a4.w};
            float bv[4] = {b4.x, b4.y, b4.z, b4.w};
#pragma unroll
            for (int r = 0; r < 4; r++)
#pragma unroll
                for (int c = 0; c < 4; c++) acc[r][c] += av[r] * bv[c];
        }
    }

    const int sect = n0 >> 9;                // 0=q, 1=k, 2=v
    const int h    = (n0 >> 6) & 7;
    const int b    = m0 >> 10;
    const int i0   = m0 & 1023;

    if (sect == 2) {
        // transpose through LDS -> vT[b][h][d][j] (bf16)
        __syncthreads();
        float* T = smem;                     // [64][68]
#pragma unroll
        for (int r = 0; r < 4; r++)
#pragma unroll
            for (int c = 0; c < 4; c++)
                T[(tx * 4 + c) * 68 + (ty * 4 + r)] = acc[r][c];
        __syncthreads();
        const int dp = t >> 2, iq = (t & 3) * 16;
        unsigned short* dst = vtbus + (((size_t)(b * 8 + h)) * 64 + dp) * 1024 + i0 + iq;
#pragma unroll
        for (int u = 0; u < 4; u++) {
            float4 f = *(float4*)&T[dp * 68 + iq + u * 4];
            uint2 pkd; pkd.x = pk2(f.x, f.y); pkd.y = pk2(f.z, f.w);
            *(uint2*)&dst[u * 4] = pkd;
        }
    } else {
        unsigned short* dst = (sect == 0) ? qbus : kbus;
        const float sc = (sect == 0) ? 0.125f : 1.0f;   // 1/sqrt(64) folded into q
#pragma unroll
        for (int r = 0; r < 4; r++) {
            const int i = i0 + ty * 4 + r;
#pragma unroll
            for (int c = 0; c < 4; c += 2) {
                unsigned u = pk2(acc[r][c] * sc, acc[r][c + 1] * sc);
                *(unsigned*)&dst[(((size_t)(b * 8 + h)) * 1024 + i) * 64 + tx * 4 + c] = u;
            }
        }
    }
}

// ---------------------------------------------------------------------------
// Kernel A: pair-bias GEMM (pure HBM stream).
// bias[b][h][i][j] (bf16) = sum_p pair[b][i][j][p] * Wb[p][h]
// Flat row r = (b*1024+i)*1024 + j; 16-row groups -> one 16x16x32 MFMA pair.
// Wave u handles 16 contiguous groups (64 KB contiguous read). No LDS,
// no barriers, 2048 blocks x 256 threads (8 blocks/CU, 32 waves/CU).
// ---------------------------------------------------------------------------
__global__ __launch_bounds__(256) void bias_kernel(
    const float* __restrict__ pair, const float* __restrict__ Wb,
    unsigned short* __restrict__ biasb)
{
    const int t    = threadIdx.x;
    const int lane = t & 63;
    const int wv   = t >> 6;
    const int q4   = lane >> 4;
    const int l15  = lane & 15;

    // W_bias B-fragments (2 k-steps), col h = l15 (zero-pad h>=8)
    uint4 wbf[2];
#pragma unroll
    for (int ks = 0; ks < 2; ks++) {
        float f[8];
#pragma unroll
        for (int e = 0; e < 8; e++)
            f[e] = (l15 < 8) ? Wb[(ks * 32 + q4 * 8 + e) * 8 + l15] : 0.f;
        wbf[ks].x = pk2(f[0], f[1]); wbf[ks].y = pk2(f[2], f[3]);
        wbf[ks].z = pk2(f[4], f[5]); wbf[ks].w = pk2(f[6], f[7]);
    }

    const int u = blockIdx.x * 4 + wv;       // wave index, 8192 waves
#pragma unroll 1
    for (int g = 0; g < 16; g++) {
        const size_t Gi = (size_t)u * 16 + g;       // group index
        const size_t r0 = Gi * 16;                  // first flat row
        const float* rp = pair + (r0 + l15) * 64;   // lane's row

        f32x4 c = {0.f, 0.f, 0.f, 0.f};
#pragma unroll
        for (int ks = 0; ks < 2; ks++) {
            float4 fa = *(const float4*)(rp + ks * 32 + q4 * 8);
            float4 fb = *(const float4*)(rp + ks * 32 + q4 * 8 + 4);
            uint4 af;
            af.x = pk2(fa.x, fa.y); af.y = pk2(fa.z, fa.w);
            af.z = pk2(fb.x, fb.y); af.w = pk2(fb.z, fb.w);
            c = __builtin_amdgcn_mfma_f32_16x16x32_bf16(*(bf16x8*)&af, *(bf16x8*)&wbf[ks], c, 0, 0, 0);
        }

        if (l15 < 8) {
            const int b   = (int)(r0 >> 20);
            const int i   = (int)((r0 >> 10) & 1023);
            const int j0g = (int)(r0 & 1023);
            unsigned short* dp = biasb + ((((size_t)(b * 8 + l15)) * 1024 + i) << 10)
                               + j0g + q4 * 4;
            *(unsigned*)dp       = pk2(c[0], c[1]);
            *(unsigned*)(dp + 2) = pk2(c[2], c[3]);
        }
    }
}

// ---------------------------------------------------------------------------
// Kernel B: attention with precomputed bias. Barrier-free: wave = head.
// grid = 256 blocks x 512 thr = 2048 waves = (b, i-tile of 16, jh) x 8 heads.
// Per j-tile of 32: bias C-init (bf16 loads, streamed once), QK/PV via MFMA
// (all 16 rows valid), online softmax, partial (m,l,ctx) out for merge.
// ---------------------------------------------------------------------------
__global__ __launch_bounds__(512, 2) void attn_kernel(
    const unsigned short* __restrict__ biasb, const unsigned short* __restrict__ qbus,
    const unsigned short* __restrict__ kbus, const unsigned short* __restrict__ vtbus,
    float* __restrict__ cp, float* __restrict__ mlm, float* __restrict__ mll)
{
    __shared__ __align__(16) unsigned short pbuf[8 * 16 * 40]; // [wave][i16][j pad 40]

    const int t    = threadIdx.x;
    const int lane = t & 63;
    const int w    = t >> 6;                 // wave id == head
    const int q4   = lane >> 4;
    const int l15  = lane & 15;

    // XCD swizzle: XCD x gets vbid [32x,32x+32) -> one batch per XCD group,
    // K/V (2 MB/batch) L2-resident.
    const int bx   = blockIdx.x;
    const int vbid = ((bx & 7) << 5) | (bx >> 3);
    const int b    = vbid >> 7;
    const int rem  = vbid & 127;
    const int jh   = rem >> 6;               // j-half
    const int i0   = (rem & 63) * 16;        // i-tile of 16

    // Q A-fragments: row i = i0 + l15 (all valid), k = d
    uint4 qf[2];
    {
        const unsigned short* qrow = qbus + (size_t)((b * 8 + w) * 1024 + i0 + l15) * 64;
#pragma unroll
        for (int ks = 0; ks < 2; ks++)
            qf[ks] = *(const uint4*)(qrow + ks * 32 + q4 * 8);
    }

    f32x4 acc[4];
#pragma unroll
    for (int dn = 0; dn < 4; dn++) acc[dn] = (f32x4){0.f, 0.f, 0.f, 0.f};
    float mrun[4], lrun[4];
#pragma unroll
    for (int rr = 0; rr < 4; rr++) { mrun[rr] = -3.0e38f; lrun[rr] = 0.f; }

    const unsigned short* kbase = kbus + (size_t)((b * 8 + w) * 1024 + jh * 512) * 64;
    const unsigned short* vbase = vtbus + (size_t)((b * 8 + w) * 64) * 1024 + jh * 512;
    const unsigned short* bbase = biasb + ((size_t)((b * 8 + w) * 1024 + i0)) * 1024 + jh * 512;

    for (int jt = 0; jt < 16; jt++) {
        const int j0 = jt * 32;

        // ---- bias C-init (bf16 -> f32), rows i = q4*4+rr, cols j0+l15(+16) ----
        f32x4 s0, s1;
#pragma unroll
        for (int rr = 0; rr < 4; rr++) {
            const unsigned short* bp = bbase + (size_t)(q4 * 4 + rr) * 1024 + j0;
            s0[rr] = BFLO(bp[l15]);
            s1[rr] = BFLO(bp[16 + l15]);
        }

        // ---- K/V fragments ----
        uint4 kf[2][2], vf[4];
        {
            const unsigned short* kt = kbase + (size_t)(j0 + l15) * 64;
#pragma unroll
            for (int jn = 0; jn < 2; jn++)
#pragma unroll
                for (int ks = 0; ks < 2; ks++)
                    kf[jn][ks] = *(const uint4*)(kt + jn * 16 * 64 + ks * 32 + q4 * 8);
#pragma unroll
            for (int dn = 0; dn < 4; dn++)
                vf[dn] = *(const uint4*)(vbase + (size_t)(dn * 16 + l15) * 1024 + j0 + q4 * 8);
        }

        // ---- QK via MFMA (C-init = bias) ----
        s0 = __builtin_amdgcn_mfma_f32_16x16x32_bf16(*(bf16x8*)&qf[0], *(bf16x8*)&kf[0][0], s0, 0, 0, 0);
        s0 = __builtin_amdgcn_mfma_f32_16x16x32_bf16(*(bf16x8*)&qf[1], *(bf16x8*)&kf[0][1], s0, 0, 0, 0);
        s1 = __builtin_amdgcn_mfma_f32_16x16x32_bf16(*(bf16x8*)&qf[0], *(bf16x8*)&kf[1][0], s1, 0, 0, 0);
        s1 = __builtin_amdgcn_mfma_f32_16x16x32_bf16(*(bf16x8*)&qf[1], *(bf16x8*)&kf[1][1], s1, 0, 0, 0);

        // ---- online softmax (rows = q4*4+rr; reduce over 16-lane groups) ----
#pragma unroll
        for (int rr = 0; rr < 4; rr++) {
            float x = fmaxf(s0[rr], s1[rr]);
            x = fmaxf(x, __shfl_xor(x, 1));
            x = fmaxf(x, __shfl_xor(x, 2));
            x = fmaxf(x, __shfl_xor(x, 4));
            x = fmaxf(x, __shfl_xor(x, 8));
            const float mnew = fmaxf(mrun[rr], x);
            const float corr = __expf(mrun[rr] - mnew);
            mrun[rr] = mnew;
            const float p0 = __expf(s0[rr] - mnew);
            const float p1 = __expf(s1[rr] - mnew);
            float ts = p0 + p1;
            ts += __shfl_xor(ts, 1);
            ts += __shfl_xor(ts, 2);
            ts += __shfl_xor(ts, 4);
            ts += __shfl_xor(ts, 8);
            lrun[rr] = lrun[rr] * corr + ts;
#pragma unroll
            for (int dn = 0; dn < 4; dn++) acc[dn][rr] *= corr;
            unsigned short* pb = &pbuf[(w * 16 + q4 * 4 + rr) * 40];
            pb[l15]      = __bfloat16_as_ushort(__float2bfloat16(p0));
            pb[16 + l15] = __bfloat16_as_ushort(__float2bfloat16(p1));
        }

        // ---- P writes -> A-frag read (same wave, cross-lane) ----
        asm volatile("s_waitcnt lgkmcnt(0)" ::: "memory");
        __builtin_amdgcn_sched_barrier(0);

        bf16x8 pfrag = *(bf16x8*)&pbuf[(w * 16 + l15) * 40 + q4 * 8];
        // ensure the read completed before next iteration's overwrites
        asm volatile("s_waitcnt lgkmcnt(0)" ::: "memory");
        __builtin_amdgcn_sched_barrier(0);

#pragma unroll
        for (int dn = 0; dn < 4; dn++)
            acc[dn] = __builtin_amdgcn_mfma_f32_16x16x32_bf16(pfrag, *(bf16x8*)&vf[dn], acc[dn], 0, 0, 0);
    }

    // ---- epilogue: un-normalized partial + (m,l), all 16 rows valid ----
#pragma unroll
    for (int rr = 0; rr < 4; rr++) {
        const int i = q4 * 4 + rr;
        float* crow = cp + (size_t)jh * (2048 * 512)
                    + ((size_t)(b * 1024) + i0 + i) * 512 + w * 64;
#pragma unroll
        for (int dn = 0; dn < 4; dn++)
            crow[dn * 16 + l15] = acc[dn][rr];
        if (l15 == 0) {
            const int mi = ((jh * 2 + b) * 8 + w) * 1024 + i0 + i;
            mlm[mi] = mrun[rr];
            mll[mi] = lrun[rr];
        }
    }
}

// ---------------------------------------------------------------------------
// Kernel 2b: merge the two j-half partials.
// out = (c0*e^{m0-M} + c1*e^{m1-M}) / (l0*e^{m0-M} + l1*e^{m1-M})
// ---------------------------------------------------------------------------
__global__ __launch_bounds__(256) void merge_kernel(
    const float* __restrict__ cp, const float* __restrict__ mlm,
    const float* __restrict__ mll, float* __restrict__ ctx)
{
    const int row = blockIdx.x;              // b*1024 + i
    const int b   = row >> 10, i = row & 1023;
    const int t   = threadIdx.x;
    const int h   = t >> 5;                  // e0 = t*2 -> h = e0>>6

    const int mi0 = ((0 * 2 + b) * 8 + h) * 1024 + i;
    const int mi1 = ((1 * 2 + b) * 8 + h) * 1024 + i;
    const float m0 = mlm[mi0], m1 = mlm[mi1];
    const float l0 = mll[mi0], l1 = mll[mi1];
    const float M  = fmaxf(m0, m1);
    const float w0 = __expf(m0 - M), w1 = __expf(m1 - M);
    const float inv = 1.0f / (l0 * w0 + l1 * w1);

    const float2 c0 = *(const float2*)&cp[(size_t)row * 512 + t * 2];
    const float2 c1 = *(const float2*)&cp[(size_t)(2048 * 512) + (size_t)row * 512 + t * 2];
    float2 o;
    o.x = (c0.x * w0 + c1.x * w1) * inv;
    o.y = (c0.y * w0 + c1.y * w1) * inv;
    *(float2*)&ctx[(size_t)row * 512 + t * 2] = o;
}

// ---------------------------------------------------------------------------
// Kernel 3: out = ctx[2048][512] @ W_out[512][512] + b_out
// ---------------------------------------------------------------------------
__global__ __launch_bounds__(256, 2) void gemm_out_kernel(
    const float* __restrict__ A, const float* __restrict__ W,
    const float* __restrict__ bias, float* __restrict__ out)
{
    __shared__ float smem[64 * 68];
    float* As = smem;
    float* Bs = smem + 32 * 68;

    const int t  = threadIdx.x;
    const int m0 = blockIdx.y * 64;
    const int n0 = blockIdx.x * 64;
    const int tx = t & 15, ty = t >> 4;

    const int am = t >> 2, ak = (t & 3) * 8;
    const int bk = t >> 3, bn = (t & 7) * 8;

    float acc[4][4] = {};

    for (int k0 = 0; k0 < 512; k0 += 32) {
        float4 a0 = *(const float4*)&A[(size_t)(m0 + am) * 512 + k0 + ak];
        float4 a1 = *(const float4*)&A[(size_t)(m0 + am) * 512 + k0 + ak + 4];
        float4 b0 = *(const float4*)&W[(size_t)(k0 + bk) * 512 + n0 + bn];
        float4 b1 = *(const float4*)&W[(size_t)(k0 + bk) * 512 + n0 + bn + 4];
        __syncthreads();
        As[(ak + 0) * 68 + am] = a0.x;
        As[(ak + 1) * 68 + am] = a0.y;
        As[(ak + 2) * 68 + am] = a0.z;
        As[(ak + 3) * 68 + am] = a0.w;
        As[(ak + 4) * 68 + am] = a1.x;
        As[(ak + 5) * 68 + am] = a1.y;
        As[(ak + 6) * 68 + am] = a1.z;
        As[(ak + 7) * 68 + am] = a1.w;
        *(float4*)&Bs[bk * 68 + bn]     = b0;
        *(float4*)&Bs[bk * 68 + bn + 4] = b1;
        __syncthreads();
#pragma unroll
        for (int kk = 0; kk < 32; kk++) {
            float4 a4 = *(float4*)&As[kk * 68 + ty * 4];
            float4 b4 = *(float4*)&Bs[kk * 68 + tx * 4];
            float av[4] = {a4.x, a4.y, a4.z, a4.w};
            float bv[4] = {b4.x, b4.y, b4.z, b4.w};
#pragma unroll
            for (int r = 0; r < 4; r++)
#pragma unroll
                for (int c = 0; c < 4; c++) acc[r][c] += av[r] * bv[c];
        }
    }

    float4 bo = *(const float4*)&bias[n0 + tx * 4];
    float bv[4] = {bo.x, bo.y, bo.z, bo.w};
#pragma unroll
    for (int r = 0; r < 4; r++) {
        const int m = m0 + ty * 4 + r;
#pragma unroll
        for (int c = 0; c < 4; c++)
            out[(size_t)m * 512 + n0 + tx * 4 + c] = acc[r][c] + bv[c];
    }
}

// ---------------------------------------------------------------------------
extern "C" void kernel_launch(void* const* d_in, const int* in_sizes, int n_in,
                              void* d_out, int out_size, void* d_ws, size_t ws_size,
                              hipStream_t stream)
{
    const float* seq  = (const float*)d_in[0];
    const float* pair = (const float*)d_in[1];
    const float* Wqkv = (const float*)d_in[2];
    const float* Wb   = (const float*)d_in[3];
    const float* Wout = (const float*)d_in[4];
    const float* bout = (const float*)d_in[5];
    float* out = (float*)d_out;

    unsigned short* qbus  = (unsigned short*)d_ws;           // bf16 [2][8][1024][64]   2 MB
    unsigned short* kbus  = qbus + (1 << 20);                // bf16 [2][8][1024][64]   2 MB
    unsigned short* vtbus = kbus + (1 << 20);                // bf16 [2][8][64][1024]   2 MB
    float*          ctx   = (float*)(vtbus + (1 << 20));     // fp32 [2][1024][512]     4 MB
    float*          cp    = ctx + (1 << 20);                 // fp32 [2][2048][512]     8 MB
    float*          mlm   = cp + (2 << 20);                  // fp32 [2][2][8][1024]  128 KB
    float*          mll   = mlm + (1 << 15);                 // fp32 [2][2][8][1024]  128 KB
    unsigned short* biasb = (unsigned short*)(mll + (1 << 15)); // bf16 [2][8][1024][1024] 32 MB

    gemm_qkv_kernel<<<dim3(24, 32), 256, 0, stream>>>(seq, Wqkv, qbus, kbus, vtbus);
    bias_kernel<<<2048, 256, 0, stream>>>(pair, Wb, biasb);
    attn_kernel<<<256, 512, 0, stream>>>(biasb, qbus, kbus, vtbus, cp, mlm, mll);
    merge_kernel<<<2048, 256, 0, stream>>>(cp, mlm, mll, ctx);
    gemm_out_kernel<<<dim3(8, 32), 256, 0, stream>>>(ctx, Wout, bout, out);
}

// Round 8
// 239.288 us; speedup vs baseline: 1.0393x; 1.0393x over previous
//
#include <hip/hip_runtime.h>
#include <hip/hip_bf16.h>

// B=2, L=1024, E=512, H=8, D=64, P=64
// inputs: seq [2,1024,512], pair [2,1024,1024,64], W_qkv [512,1536],
//         W_bias [64,8], W_out [512,512], b_out [512]   (all fp32)

typedef __attribute__((ext_vector_type(8))) short bf16x8;
typedef __attribute__((ext_vector_type(4))) float f32x4;

#define BFLO(u) __uint_as_float(((unsigned)(u)) << 16)

__device__ __forceinline__ unsigned pk2(float a, float b) {
    __hip_bfloat16 ha = __float2bfloat16(a);
    __hip_bfloat16 hb = __float2bfloat16(b);
    return (unsigned)__bfloat16_as_ushort(ha) | ((unsigned)__bfloat16_as_ushort(hb) << 16);
}

// nt pair staging (zero-reuse stream)
__device__ __forceinline__ void gl16_nt(const void* g, void* l) {
    __builtin_amdgcn_global_load_lds((const __attribute__((address_space(1))) void*)g,
                                     (__attribute__((address_space(3))) void*)l, 16, 0, 2);
}

// ---------------------------------------------------------------------------
// Kernel 1: QKV GEMM.  A[2048][512] @ W[512][1536] ->
//   q bf16 [B][H][L][D] (x1/8), k bf16 [B][H][L][D], vT bf16 [B][H][D][L]
// ---------------------------------------------------------------------------
__global__ __launch_bounds__(256, 2) void gemm_qkv_kernel(
    const float* __restrict__ A, const float* __restrict__ W,
    unsigned short* __restrict__ qbus, unsigned short* __restrict__ kbus,
    unsigned short* __restrict__ vtbus)
{
    __shared__ float smem[64 * 68];
    float* As = smem;                        // As[k][m]
    float* Bs = smem + 32 * 68;              // Bs[k][n]

    const int t  = threadIdx.x;
    const int m0 = blockIdx.y * 64;
    const int n0 = blockIdx.x * 64;
    const int tx = t & 15, ty = t >> 4;

    const int am = t >> 2, ak = (t & 3) * 8;
    const int bk = t >> 3, bn = (t & 7) * 8;

    float acc[4][4] = {};

    for (int k0 = 0; k0 < 512; k0 += 32) {
        float4 a0 = *(const float4*)&A[(size_t)(m0 + am) * 512 + k0 + ak];
        float4 a1 = *(const float4*)&A[(size_t)(m0 + am) * 512 + k0 + ak + 4];
        float4 b0 = *(const float4*)&W[(size_t)(k0 + bk) * 1536 + n0 + bn];
        float4 b1 = *(const float4*)&W[(size_t)(k0 + bk) * 1536 + n0 + bn + 4];
        __syncthreads();
        As[(ak + 0) * 68 + am] = a0.x;
        As[(ak + 1) * 68 + am] = a0.y;
        As[(ak + 2) * 68 + am] = a0.z;
        As[(ak + 3) * 68 + am] = a0.w;
        As[(ak + 4) * 68 + am] = a1.x;
        As[(ak + 5) * 68 + am] = a1.y;
        As[(ak + 6) * 68 + am] = a1.z;
        As[(ak + 7) * 68 + am] = a1.w;
        *(float4*)&Bs[bk * 68 + bn]     = b0;
        *(float4*)&Bs[bk * 68 + bn + 4] = b1;
        __syncthreads();
#pragma unroll
        for (int kk = 0; kk < 32; kk++) {
            float4 a4 = *(float4*)&As[kk * 68 + ty * 4];
            float4 b4 = *(float4*)&Bs[kk * 68 + tx * 4];
            float av[4] = {a4.x, a4.y, a4.z, a4.w};
            float bv[4] = {b4.x, b4.y, b4.z, b4.w};
#pragma unroll
            for (int r = 0; r < 4; r++)
#pragma unroll
                for (int c = 0; c < 4; c++) acc[r][c] += av[r] * bv[c];
        }
    }

    const int sect = n0 >> 9;                // 0=q, 1=k, 2=v
    const int h    = (n0 >> 6) & 7;
    const int b    = m0 >> 10;
    const int i0   = m0 & 1023;

    if (sect == 2) {
        __syncthreads();
        float* T = smem;                     // [64][68]
#pragma unroll
        for (int r = 0; r < 4; r++)
#pragma unroll
            for (int c = 0; c < 4; c++)
                T[(tx * 4 + c) * 68 + (ty * 4 + r)] = acc[r][c];
        __syncthreads();
        const int dp = t >> 2, iq = (t & 3) * 16;
        unsigned short* dst = vtbus + (((size_t)(b * 8 + h)) * 64 + dp) * 1024 + i0 + iq;
#pragma unroll
        for (int u = 0; u < 4; u++) {
            float4 f = *(float4*)&T[dp * 68 + iq + u * 4];
            uint2 pkd; pkd.x = pk2(f.x, f.y); pkd.y = pk2(f.z, f.w);
            *(uint2*)&dst[u * 4] = pkd;
        }
    } else {
        unsigned short* dst = (sect == 0) ? qbus : kbus;
        const float sc = (sect == 0) ? 0.125f : 1.0f;
#pragma unroll
        for (int r = 0; r < 4; r++) {
            const int i = i0 + ty * 4 + r;
#pragma unroll
            for (int c = 0; c < 4; c += 2) {
                unsigned u = pk2(acc[r][c] * sc, acc[r][c + 1] * sc);
                *(unsigned*)&dst[(((size_t)(b * 8 + h)) * 1024 + i) * 64 + tx * 4 + c] = u;
            }
        }
    }
}

// slab fragment: logical p-slots (ks*8+q4*2, +1) of row, XOR-swizzled by sw
__device__ __forceinline__ bf16x8 slab_frag(const char* rowb, int ks, int q4, int sw) {
    const int s0 = ks * 8 + q4 * 2;
    const float4 fa = *(const float4*)(rowb + (((s0    ) ^ sw) << 4));
    const float4 fb = *(const float4*)(rowb + (((s0 + 1) ^ sw) << 4));
    uint4 u;
    u.x = pk2(fa.x, fa.y); u.y = pk2(fa.z, fa.w);
    u.z = pk2(fb.x, fb.y); u.w = pk2(fb.z, fb.w);
    return *(bf16x8*)&u;
}

// ---------------------------------------------------------------------------
// Kernel 2: fused pair-bias flash attention, SELF-STAGED pipeline.
// grid 512 = (b, i-tile of 8, j-half) -> 2 blocks/CU. 512 thr = 8 waves.
// Wave w stages AND bias-computes slab rows ii=w (16 j-rows, 4KB, 4 gl_lds)
// -> stage wait is per-wave counted vmcnt (never 0); barriers only guard
// bias_lds. Per j-tile of 16: bias MFMA -> barrier -> QK (C=bias) -> softmax
// -> PV. Outputs unnormalized partials + (m,l) per j-half.
// ---------------------------------------------------------------------------
__global__ __launch_bounds__(512, 4) void attn_kernel(
    const float* __restrict__ pair, const float* __restrict__ Wb,
    const unsigned short* __restrict__ qbus, const unsigned short* __restrict__ kbus,
    const unsigned short* __restrict__ vtbus, float* __restrict__ cp,
    float* __restrict__ mlm, float* __restrict__ mll)
{
    __shared__ __align__(16) char plds[2][32768];             // [128 rows][16 slots]
    __shared__ __align__(16) unsigned short bias_lds[128 * 17]; // [row=ii*16+j][h pad17] bf16
    __shared__ __align__(16) unsigned short pbuf[8 * 16 * 24];  // [w][i16][j pad24] bf16

    const int t    = threadIdx.x;
    const int lane = t & 63;
    const int w    = t >> 6;            // wave id == ii (stage/bias) == head (QK/PV)
    const int q4   = lane >> 4;
    const int l15  = lane & 15;

    const int bx   = blockIdx.x;
    const int vbid = ((bx & 7) << 6) | (bx >> 3);   // XCD-contiguous
    const int b    = vbid >> 8;
    const int rem  = vbid & 255;
    const int jh   = rem >> 7;
    const int i0   = (rem & 127) * 8;

    // W_bias B-frags (B col = h = l15, pad h>=8)
    uint4 wbf[2];
#pragma unroll
    for (int ks = 0; ks < 2; ks++) {
        float f[8];
#pragma unroll
        for (int e = 0; e < 8; e++)
            f[e] = (l15 < 8) ? Wb[(ks * 32 + q4 * 8 + e) * 8 + l15] : 0.f;
        wbf[ks].x = pk2(f[0], f[1]); wbf[ks].y = pk2(f[2], f[3]);
        wbf[ks].z = pk2(f[4], f[5]); wbf[ks].w = pk2(f[6], f[7]);
    }

    // Q A-frags: rows i = i0 + l15 (8 valid)
    uint4 qf[2] = {};
    if (l15 < 8) {
        const unsigned short* qrow = qbus + (size_t)((b * 8 + w) * 1024 + i0 + l15) * 64;
#pragma unroll
        for (int ks = 0; ks < 2; ks++)
            qf[ks] = *(const uint4*)(qrow + ks * 32 + q4 * 8);
    }

    // resolve prologue loads so loop vmcnt accounting is exact
    asm volatile("s_waitcnt vmcnt(0)" ::: "memory");
    __builtin_amdgcn_sched_barrier(0);

    // staging: wave w owns pair row i0+w; per instr r: 4 j-rows (jl = r*4+q4),
    // phys slot l15 holds logical slot l15^jl (XOR pre-swizzled global source)
    const char* prow = (const char*)pair
                     + ((size_t)(b * 1024 + i0 + w) * 1024 + jh * 512) * 256;
    int soff[4];
#pragma unroll
    for (int r = 0; r < 4; r++) {
        const int jl = r * 4 + q4;
        soff[r] = jl * 256 + ((l15 ^ jl) << 4);
    }
    char* ldsW = (char*)plds + w * 4096;

#define STAGE(bufsel, jtn) do {                                         \
        const char* gg = prow + (size_t)(jtn) * 4096;                   \
        char* ld = ldsW + (bufsel) * 32768;                             \
        _Pragma("unroll")                                               \
        for (int r = 0; r < 4; r++)                                     \
            gl16_nt(gg + soff[r], ld + r * 1024);                       \
    } while (0)

    STAGE(0, 0);

    f32x4 acc[4];
#pragma unroll
    for (int dn = 0; dn < 4; dn++) acc[dn] = (f32x4){0.f, 0.f, 0.f, 0.f};
    float mrun[4], lrun[4];
#pragma unroll
    for (int rr = 0; rr < 4; rr++) { mrun[rr] = -3.0e38f; lrun[rr] = 0.f; }

    const unsigned short* kbase = kbus + (size_t)((b * 8 + w) * 1024 + jh * 512) * 64;
    const unsigned short* vbase = vtbus + (size_t)((b * 8 + w) * 64) * 1024 + jh * 512;

#pragma unroll 1
    for (int jt = 0; jt < 32; jt++) {
        const char* cur = (const char*)plds + (jt & 1) * 32768;

        // ---- K/V reg loads: 6 vmem (L2-resident) ----
        uint4 kf[2], vf[4];
        {
            const unsigned short* kt = kbase + (size_t)(jt * 16 + l15) * 64;
            kf[0] = *(const uint4*)(kt + q4 * 8);
            kf[1] = *(const uint4*)(kt + 32 + q4 * 8);
#pragma unroll
            for (int dn = 0; dn < 4; dn++)
                vf[dn] = *(const uint4*)(vbase + (size_t)(dn * 16 + l15) * 1024
                                         + jt * 16 + (q4 & 1) * 8);
        }

        // ---- issue next stage; wait ONLY own stage(jt) (counted, never 0) ----
        if (jt < 31) {
            STAGE((jt + 1) & 1, jt + 1);
            asm volatile("s_waitcnt vmcnt(10)" ::: "memory");   // 6 KV + 4 next-stage live
        } else {
            asm volatile("s_waitcnt vmcnt(6)" ::: "memory");    // 6 KV live
        }
        __builtin_amdgcn_sched_barrier(0);

        // ---- bias MFMA on own rows (ii=w, 16 j) ----
        {
            const char* rowb = cur + w * 4096 + l15 * 256;
            f32x4 bb = {0.f, 0.f, 0.f, 0.f};
#pragma unroll
            for (int ks = 0; ks < 2; ks++)
                bb = __builtin_amdgcn_mfma_f32_16x16x32_bf16(
                        slab_frag(rowb, ks, q4, l15), *(bf16x8*)&wbf[ks], bb, 0, 0, 0);
            if (l15 < 8) {
#pragma unroll
                for (int rr = 0; rr < 4; rr++)   // D: row=j=q4*4+rr, col=h=l15
                    bias_lds[(w * 16 + q4 * 4 + rr) * 17 + l15] =
                        __bfloat16_as_ushort(__float2bfloat16(bb[rr]));
            }
        }

        // ---- bias visible ----
        asm volatile("s_waitcnt lgkmcnt(0)" ::: "memory");
        __builtin_amdgcn_sched_barrier(0);
        __builtin_amdgcn_s_barrier();
        __builtin_amdgcn_sched_barrier(0);

        // ---- QK (wave=head w), C-init = bias[i][j][w] ----
        f32x4 s;
#pragma unroll
        for (int rr = 0; rr < 4; rr++) {
            const int ii = q4 * 4 + rr;
            s[rr] = (q4 < 2) ? BFLO(bias_lds[(ii * 16 + l15) * 17 + w]) : 0.f;
        }
        s = __builtin_amdgcn_mfma_f32_16x16x32_bf16(*(bf16x8*)&qf[0], *(bf16x8*)&kf[0], s, 0, 0, 0);
        s = __builtin_amdgcn_mfma_f32_16x16x32_bf16(*(bf16x8*)&qf[1], *(bf16x8*)&kf[1], s, 0, 0, 0);

        // ---- online softmax (16-lane j groups; rows i = q4*4+rr) ----
#pragma unroll
        for (int rr = 0; rr < 4; rr++) {
            float x = s[rr];
            x = fmaxf(x, __shfl_xor(x, 1));
            x = fmaxf(x, __shfl_xor(x, 2));
            x = fmaxf(x, __shfl_xor(x, 4));
            x = fmaxf(x, __shfl_xor(x, 8));
            const float mnew = fmaxf(mrun[rr], x);
            const float corr = __expf(mrun[rr] - mnew);
            mrun[rr] = mnew;
            const float p0 = __expf(s[rr] - mnew);
            float ts = p0;
            ts += __shfl_xor(ts, 1);
            ts += __shfl_xor(ts, 2);
            ts += __shfl_xor(ts, 4);
            ts += __shfl_xor(ts, 8);
            lrun[rr] = lrun[rr] * corr + ts;
#pragma unroll
            for (int dn = 0; dn < 4; dn++) acc[dn][rr] *= corr;
            pbuf[(w * 16 + q4 * 4 + rr) * 24 + l15] =
                __bfloat16_as_ushort(__float2bfloat16(p0));
        }

        // ---- P write -> A-frag read (same wave) ----
        asm volatile("s_waitcnt lgkmcnt(0)" ::: "memory");
        __builtin_amdgcn_sched_barrier(0);

        bf16x8 pfrag = (bf16x8){0, 0, 0, 0, 0, 0, 0, 0};
        if (q4 < 2) pfrag = *(bf16x8*)&pbuf[(w * 16 + l15) * 24 + q4 * 8];
#pragma unroll
        for (int dn = 0; dn < 4; dn++)
            acc[dn] = __builtin_amdgcn_mfma_f32_16x16x32_bf16(pfrag, *(bf16x8*)&vf[dn], acc[dn], 0, 0, 0);

        // ---- protect bias_lds before next tile's overwrite ----
        __builtin_amdgcn_s_barrier();
    }

    // ---- epilogue: unnormalized partials + (m,l) ----
    if (q4 < 2) {
#pragma unroll
        for (int rr = 0; rr < 4; rr++) {
            const int i = q4 * 4 + rr;
            float* crow = cp + (size_t)jh * (2048 * 512)
                        + ((size_t)(b * 1024) + i0 + i) * 512 + w * 64;
#pragma unroll
            for (int dn = 0; dn < 4; dn++)
                crow[dn * 16 + l15] = acc[dn][rr];
            if (l15 == 0) {
                const int mi = ((jh * 2 + b) * 8 + w) * 1024 + i0 + i;
                mlm[mi] = mrun[rr];
                mll[mi] = lrun[rr];
            }
        }
    }
#undef STAGE
}

// ---------------------------------------------------------------------------
// Kernel 3: fused merge + out-proj.
// A-row = merge(cp0,cp1) via (m,l); out = A @ W_out + b_out.
// ---------------------------------------------------------------------------
__global__ __launch_bounds__(256, 2) void gemm_out_fused(
    const float* __restrict__ cp, const float* __restrict__ mlm,
    const float* __restrict__ mll, const float* __restrict__ W,
    const float* __restrict__ bias, float* __restrict__ out)
{
    __shared__ float smem[64 * 68];
    float* As = smem;
    float* Bs = smem + 32 * 68;

    const int t  = threadIdx.x;
    const int m0 = blockIdx.y * 64;
    const int n0 = blockIdx.x * 64;
    const int tx = t & 15, ty = t >> 4;

    const int am = t >> 2, ak = (t & 3) * 8;
    const int bk = t >> 3, bn = (t & 7) * 8;

    const int row = m0 + am;                 // flat b*1024+i
    const int bb  = row >> 10, ii = row & 1023;
    const float* cp0 = cp + (size_t)row * 512;
    const float* cp1 = cp + (size_t)(2048 * 512) + (size_t)row * 512;

    float acc[4][4] = {};
    float w0 = 0.f, w1 = 0.f;

    for (int k0 = 0; k0 < 512; k0 += 32) {
        if ((k0 & 63) == 0) {                // new head every 64 e
            const int h   = k0 >> 6;
            const int mi0 = ((bb) * 8 + h) * 1024 + ii;
            const int mi1 = ((2 + bb) * 8 + h) * 1024 + ii;
            const float m0_ = mlm[mi0], m1_ = mlm[mi1];
            const float l0_ = mll[mi0], l1_ = mll[mi1];
            const float M   = fmaxf(m0_, m1_);
            float e0 = __expf(m0_ - M), e1 = __expf(m1_ - M);
            const float inv = 1.0f / (l0_ * e0 + l1_ * e1);
            w0 = e0 * inv; w1 = e1 * inv;
        }
        float4 c0a = *(const float4*)&cp0[k0 + ak];
        float4 c0b = *(const float4*)&cp0[k0 + ak + 4];
        float4 c1a = *(const float4*)&cp1[k0 + ak];
        float4 c1b = *(const float4*)&cp1[k0 + ak + 4];
        float4 b0 = *(const float4*)&W[(size_t)(k0 + bk) * 512 + n0 + bn];
        float4 b1 = *(const float4*)&W[(size_t)(k0 + bk) * 512 + n0 + bn + 4];
        float a0x = c0a.x * w0 + c1a.x * w1, a0y = c0a.y * w0 + c1a.y * w1;
        float a0z = c0a.z * w0 + c1a.z * w1, a0w = c0a.w * w0 + c1a.w * w1;
        float a1x = c0b.x * w0 + c1b.x * w1, a1y = c0b.y * w0 + c1b.y * w1;
        float a1z = c0b.z * w0 + c1b.z * w1, a1w = c0b.w * w0 + c1b.w * w1;
        __syncthreads();
        As[(ak + 0) * 68 + am] = a0x;
        As[(ak + 1) * 68 + am] = a0y;
        As[(ak + 2) * 68 + am] = a0z;
        As[(ak + 3) * 68 + am] = a0w;
        As[(ak + 4) * 68 + am] = a1x;
        As[(ak + 5) * 68 + am] = a1y;
        As[(ak + 6) * 68 + am] = a1z;
        As[(ak + 7) * 68 + am] = a1w;
        *(float4*)&Bs[bk * 68 + bn]     = b0;
        *(float4*)&Bs[bk * 68 + bn + 4] = b1;
        __syncthreads();
#pragma unroll
        for (int kk = 0; kk < 32; kk++) {
            float4 a4 = *(float4*)&As[kk * 68 + ty * 4];
            float4 b4 = *(float4*)&Bs[kk * 68 + tx * 4];
            float av[4] = {a4.x, a4.y, a4.z, a4.w};
            float bv[4] = {b4.x, b4.y, b4.z, b4.w};
#pragma unroll
            for (int r = 0; r < 4; r++)
#pragma unroll
                for (int c = 0; c < 4; c++) acc[r][c] += av[r] * bv[c];
        }
    }

    float4 bo = *(const float4*)&bias[n0 + tx * 4];
    float bv[4] = {bo.x, bo.y, bo.z, bo.w};
#pragma unroll
    for (int r = 0; r < 4; r++) {
        const int m = m0 + ty * 4 + r;
#pragma unroll
        for (int c = 0; c < 4; c++)
            out[(size_t)m * 512 + n0 + tx * 4 + c] = acc[r][c] + bv[c];
    }
}

// ---------------------------------------------------------------------------
extern "C" void kernel_launch(void* const* d_in, const int* in_sizes, int n_in,
                              void* d_out, int out_size, void* d_ws, size_t ws_size,
                              hipStream_t stream)
{
    const float* seq  = (const float*)d_in[0];
    const float* pair = (const float*)d_in[1];
    const float* Wqkv = (const float*)d_in[2];
    const float* Wb   = (const float*)d_in[3];
    const float* Wout = (const float*)d_in[4];
    const float* bout = (const float*)d_in[5];
    float* out = (float*)d_out;

    unsigned short* qbus  = (unsigned short*)d_ws;           // bf16 [2][8][1024][64]   2 MB
    unsigned short* kbus  = qbus + (1 << 20);                // bf16 [2][8][1024][64]   2 MB
    unsigned short* vtbus = kbus + (1 << 20);                // bf16 [2][8][64][1024]   2 MB
    float*          cp    = (float*)(vtbus + (1 << 20));     // fp32 [2][2048][512]     8 MB
    float*          mlm   = cp + (2 << 20);                  // fp32 [2][2][8][1024]  128 KB
    float*          mll   = mlm + (1 << 15);                 // fp32 [2][2][8][1024]  128 KB

    gemm_qkv_kernel<<<dim3(24, 32), 256, 0, stream>>>(seq, Wqkv, qbus, kbus, vtbus);
    attn_kernel<<<512, 512, 0, stream>>>(pair, Wb, qbus, kbus, vtbus, cp, mlm, mll);
    gemm_out_fused<<<dim3(8, 32), 256, 0, stream>>>(cp, mlm, mll, Wout, bout, out);
}

// Round 9
// 232.751 us; speedup vs baseline: 1.0685x; 1.0281x over previous
//
#include <hip/hip_runtime.h>
#include <hip/hip_bf16.h>

// B=2, L=1024, E=512, H=8, D=64, P=64
// inputs: seq [2,1024,512], pair [2,1024,1024,64], W_qkv [512,1536],
//         W_bias [64,8], W_out [512,512], b_out [512]   (all fp32)

typedef __attribute__((ext_vector_type(8))) short bf16x8;
typedef __attribute__((ext_vector_type(4))) float f32x4;

#define BFLO(u) __uint_as_float(((unsigned)(u)) << 16)

__device__ __forceinline__ unsigned pk2(float a, float b) {
    __hip_bfloat16 ha = __float2bfloat16(a);
    __hip_bfloat16 hb = __float2bfloat16(b);
    return (unsigned)__bfloat16_as_ushort(ha) | ((unsigned)__bfloat16_as_ushort(hb) << 16);
}

__device__ __forceinline__ void gl16_nt(const void* g, void* l) {
    __builtin_amdgcn_global_load_lds((const __attribute__((address_space(1))) void*)g,
                                     (__attribute__((address_space(3))) void*)l, 16, 0, 2);
}

// ---------------------------------------------------------------------------
// Kernel 0: prep — seq fp32 -> bf16 [2048][512]; W_qkv -> bf16 Wt[1536][512]
// (transposed so QKV B-fragments are contiguous-k reads).
// ---------------------------------------------------------------------------
__global__ __launch_bounds__(256) void prep_kernel(
    const float* __restrict__ seq, const float* __restrict__ W,
    unsigned short* __restrict__ seqb, unsigned short* __restrict__ wtb)
{
    __shared__ float T[64 * 68];
    const int bx = blockIdx.x, t = threadIdx.x;
    if (bx < 512) {
        const size_t idx = ((size_t)bx * 256 + t) * 8;
        float4 f0 = *(const float4*)&seq[idx];
        float4 f1 = *(const float4*)&seq[idx + 4];
        uint4 u;
        u.x = pk2(f0.x, f0.y); u.y = pk2(f0.z, f0.w);
        u.z = pk2(f1.x, f1.y); u.w = pk2(f1.z, f1.w);
        *(uint4*)&seqb[idx] = u;
    } else {
        const int bb = bx - 512;
        const int n0 = (bb % 24) * 64, k0 = (bb / 24) * 64;
        const int kk = t >> 2, nch = (t & 3) * 16;
#pragma unroll
        for (int u = 0; u < 4; u++) {
            float4 f = *(const float4*)&W[(size_t)(k0 + kk) * 1536 + n0 + nch + u * 4];
            T[kk * 68 + nch + u * 4 + 0] = f.x;
            T[kk * 68 + nch + u * 4 + 1] = f.y;
            T[kk * 68 + nch + u * 4 + 2] = f.z;
            T[kk * 68 + nch + u * 4 + 3] = f.w;
        }
        __syncthreads();
        const int nn = t >> 2, kch = (t & 3) * 16;
#pragma unroll
        for (int u = 0; u < 4; u++) {
            float a = T[(kch + u * 4 + 0) * 68 + nn];
            float b = T[(kch + u * 4 + 1) * 68 + nn];
            float c = T[(kch + u * 4 + 2) * 68 + nn];
            float d = T[(kch + u * 4 + 3) * 68 + nn];
            uint2 p; p.x = pk2(a, b); p.y = pk2(c, d);
            *(uint2*)&wtb[(size_t)(n0 + nn) * 512 + k0 + kch + u * 4] = p;
        }
    }
}

// ---------------------------------------------------------------------------
// Kernel 1: QKV GEMM via MFMA, no LDS, no barriers.
// seqb[2048][512]bf16 @ Wt[1536][512]bf16 (B pre-transposed) ->
//   q bf16 [B][H][L][D] (x1/8), k bf16 [B][H][L][D], vT bf16 [B][H][D][L]
// grid (24,32), 256 thr = 4 waves; wave = 2x2 subtiles of 16x16.
// ---------------------------------------------------------------------------
__global__ __launch_bounds__(256) void gemm_qkv_kernel(
    const unsigned short* __restrict__ seqb, const unsigned short* __restrict__ wtb,
    unsigned short* __restrict__ qbus, unsigned short* __restrict__ kbus,
    unsigned short* __restrict__ vtbus)
{
    const int t    = threadIdx.x;
    const int lane = t & 63;
    const int wv   = t >> 6;
    const int q4   = lane >> 4;
    const int l15  = lane & 15;
    const int mw   = wv >> 1, nw = wv & 1;

    const int m0 = blockIdx.y * 64;
    const int n0 = blockIdx.x * 64;

    f32x4 acc[2][2];
#pragma unroll
    for (int a = 0; a < 2; a++)
#pragma unroll
        for (int b = 0; b < 2; b++) acc[a][b] = (f32x4){0.f, 0.f, 0.f, 0.f};

    const unsigned short* arow0 = seqb + (size_t)(m0 + mw * 32 + l15) * 512 + q4 * 8;
    const unsigned short* brow0 = wtb + (size_t)(n0 + nw * 32 + l15) * 512 + q4 * 8;

#pragma unroll 4
    for (int k0 = 0; k0 < 512; k0 += 32) {
        uint4 af[2], bf[2];
        af[0] = *(const uint4*)(arow0 + k0);
        af[1] = *(const uint4*)(arow0 + 16 * 512 + k0);
        bf[0] = *(const uint4*)(brow0 + k0);
        bf[1] = *(const uint4*)(brow0 + 16 * 512 + k0);
#pragma unroll
        for (int sm = 0; sm < 2; sm++)
#pragma unroll
            for (int sn = 0; sn < 2; sn++)
                acc[sm][sn] = __builtin_amdgcn_mfma_f32_16x16x32_bf16(
                    *(bf16x8*)&af[sm], *(bf16x8*)&bf[sn], acc[sm][sn], 0, 0, 0);
    }

    const int sect = n0 >> 9;                // 0=q, 1=k, 2=v
    const int h    = (n0 >> 6) & 7;
    const int b    = m0 >> 10;
    const int i0   = m0 & 1023;

#pragma unroll
    for (int sm = 0; sm < 2; sm++) {
#pragma unroll
        for (int sn = 0; sn < 2; sn++) {
            const int d  = nw * 32 + sn * 16 + l15;
            const int ib = i0 + mw * 32 + sm * 16 + q4 * 4;
            if (sect == 2) {
                uint2 p;
                p.x = pk2(acc[sm][sn][0], acc[sm][sn][1]);
                p.y = pk2(acc[sm][sn][2], acc[sm][sn][3]);
                *(uint2*)&vtbus[(((size_t)(b * 8 + h)) * 64 + d) * 1024 + ib] = p;
            } else {
                unsigned short* dst = (sect == 0) ? qbus : kbus;
                const float sc = (sect == 0) ? 0.125f : 1.0f;
#pragma unroll
                for (int rr = 0; rr < 4; rr++)
                    dst[(((size_t)(b * 8 + h)) * 1024 + ib + rr) * 64 + d] =
                        __bfloat16_as_ushort(__float2bfloat16(acc[sm][sn][rr] * sc));
            }
        }
    }
}

// slab fragment: logical p-slots (ks*8+q4*2, +1) of row, XOR-swizzled by sw
__device__ __forceinline__ bf16x8 slab_frag(const char* rowb, int ks, int q4, int sw) {
    const int s0 = ks * 8 + q4 * 2;
    const float4 fa = *(const float4*)(rowb + (((s0    ) ^ sw) << 4));
    const float4 fb = *(const float4*)(rowb + (((s0 + 1) ^ sw) << 4));
    uint4 u;
    u.x = pk2(fa.x, fa.y); u.y = pk2(fa.z, fa.w);
    u.z = pk2(fb.x, fb.y); u.w = pk2(fb.z, fb.w);
    return *(bf16x8*)&u;
}

// ---------------------------------------------------------------------------
// Kernel 2: fused pair-bias flash attention, ONE barrier per tile.
// Bias for tile jt+1 computed during tile jt (double-buffered bias_lds);
// stage depth 2 (stage jt+2 issued at tile jt -> 2 tile-periods of HBM slack).
// grid 512 = (b, i-tile 8, j-half), 2 blocks/CU, 8 waves; wave w stages and
// bias-computes its own pair row i0+w (wave-private plds recycling).
// ---------------------------------------------------------------------------
__global__ __launch_bounds__(512, 4) void attn_kernel(
    const float* __restrict__ pair, const float* __restrict__ Wb,
    const unsigned short* __restrict__ qbus, const unsigned short* __restrict__ kbus,
    const unsigned short* __restrict__ vtbus, float* __restrict__ cp,
    float* __restrict__ mlm, float* __restrict__ mll)
{
    __shared__ __align__(16) char plds[2][32768];               // [128 rows][16 slots]
    __shared__ __align__(16) unsigned short bias_lds[2][128 * 17]; // dbuf [row][h pad17]
    __shared__ __align__(16) unsigned short pbuf[8 * 16 * 24];  // [w][i16][j pad24]

    const int t    = threadIdx.x;
    const int lane = t & 63;
    const int w    = t >> 6;
    const int q4   = lane >> 4;
    const int l15  = lane & 15;

    const int bx   = blockIdx.x;
    const int vbid = ((bx & 7) << 6) | (bx >> 3);   // XCD-contiguous
    const int b    = vbid >> 8;
    const int rem  = vbid & 255;
    const int jh   = rem >> 7;
    const int i0   = (rem & 127) * 8;

    // W_bias B-frags (col h = l15, pad h>=8)
    uint4 wbf[2];
#pragma unroll
    for (int ks = 0; ks < 2; ks++) {
        float f[8];
#pragma unroll
        for (int e = 0; e < 8; e++)
            f[e] = (l15 < 8) ? Wb[(ks * 32 + q4 * 8 + e) * 8 + l15] : 0.f;
        wbf[ks].x = pk2(f[0], f[1]); wbf[ks].y = pk2(f[2], f[3]);
        wbf[ks].z = pk2(f[4], f[5]); wbf[ks].w = pk2(f[6], f[7]);
    }

    // Q A-frags: rows i = i0 + l15 (8 valid)
    uint4 qf[2] = {};
    if (l15 < 8) {
        const unsigned short* qrow = qbus + (size_t)((b * 8 + w) * 1024 + i0 + l15) * 64;
#pragma unroll
        for (int ks = 0; ks < 2; ks++)
            qf[ks] = *(const uint4*)(qrow + ks * 32 + q4 * 8);
    }

    // drain prologue loads so loop vmcnt accounting is exact
    asm volatile("s_waitcnt vmcnt(0)" ::: "memory");
    __builtin_amdgcn_sched_barrier(0);

    // staging: wave w owns pair row i0+w; 4 gl_lds per tile of 16 j
    const char* prow = (const char*)pair
                     + ((size_t)(b * 1024 + i0 + w) * 1024 + jh * 512) * 256;
    int soff[4];
#pragma unroll
    for (int r = 0; r < 4; r++) {
        const int jl = r * 4 + q4;
        soff[r] = jl * 256 + ((l15 ^ jl) << 4);
    }
    char* ldsW = (char*)plds + w * 4096;

#define STAGE(bufsel, jtn) do {                                         \
        const char* gg = prow + (size_t)(jtn) * 4096;                   \
        char* ld = ldsW + (bufsel) * 32768;                             \
        _Pragma("unroll")                                               \
        for (int r = 0; r < 4; r++)                                     \
            gl16_nt(gg + soff[r], ld + r * 1024);                       \
    } while (0)

#define BIASCOMP(pbsel, slot) do {                                      \
        const char* rowb = (const char*)plds + (pbsel) * 32768          \
                         + w * 4096 + l15 * 256;                        \
        f32x4 bb = {0.f, 0.f, 0.f, 0.f};                                \
        _Pragma("unroll")                                               \
        for (int ks = 0; ks < 2; ks++)                                  \
            bb = __builtin_amdgcn_mfma_f32_16x16x32_bf16(               \
                    slab_frag(rowb, ks, q4, l15), *(bf16x8*)&wbf[ks],   \
                    bb, 0, 0, 0);                                       \
        if (l15 < 8) {                                                  \
            _Pragma("unroll")                                           \
            for (int rr = 0; rr < 4; rr++)                              \
                bias_lds[slot][(w * 16 + q4 * 4 + rr) * 17 + l15] =     \
                    __bfloat16_as_ushort(__float2bfloat16(bb[rr]));     \
        }                                                               \
    } while (0)

    // prologue: stage 0 and 1; bias(0) -> slot 0
    STAGE(0, 0);
    STAGE(1, 1);
    asm volatile("s_waitcnt vmcnt(4)" ::: "memory");   // stage(0) done
    __builtin_amdgcn_sched_barrier(0);
    BIASCOMP(0, 0);
    asm volatile("s_waitcnt lgkmcnt(0)" ::: "memory");
    __builtin_amdgcn_sched_barrier(0);
    __builtin_amdgcn_s_barrier();
    __builtin_amdgcn_sched_barrier(0);

    f32x4 acc[4];
#pragma unroll
    for (int dn = 0; dn < 4; dn++) acc[dn] = (f32x4){0.f, 0.f, 0.f, 0.f};
    float mrun[4], lrun[4];
#pragma unroll
    for (int rr = 0; rr < 4; rr++) { mrun[rr] = -3.0e38f; lrun[rr] = 0.f; }

    const unsigned short* kbase = kbus + (size_t)((b * 8 + w) * 1024 + jh * 512) * 64;
    const unsigned short* vbase = vtbus + (size_t)((b * 8 + w) * 64) * 1024 + jh * 512;

#pragma unroll 1
    for (int jt = 0; jt < 32; jt++) {
        // ---- K/V reg loads: 6 vmem (L2-resident) ----
        uint4 kf[2], vf[4];
        {
            const unsigned short* kt = kbase + (size_t)(jt * 16 + l15) * 64;
            kf[0] = *(const uint4*)(kt + q4 * 8);
            kf[1] = *(const uint4*)(kt + 32 + q4 * 8);
#pragma unroll
            for (int dn = 0; dn < 4; dn++)
                vf[dn] = *(const uint4*)(vbase + (size_t)(dn * 16 + l15) * 1024
                                         + jt * 16 + (q4 & 1) * 8);
        }

        // ---- issue stage(jt+2); wait stage(jt+1) (counted, 2-period slack) ----
        if (jt < 30) {
            STAGE(jt & 1, jt + 2);
            asm volatile("s_waitcnt vmcnt(10)" ::: "memory");  // 6 KV + 4 new stage
            __builtin_amdgcn_sched_barrier(0);
            BIASCOMP((jt + 1) & 1, (jt + 1) & 1);
        } else if (jt == 30) {
            asm volatile("s_waitcnt vmcnt(6)" ::: "memory");   // 6 KV
            __builtin_amdgcn_sched_barrier(0);
            BIASCOMP(1, 1);                                    // bias(31)
        }

        // ---- QK (wave=head w), C-init = bias(jt) from slot jt&1 ----
        f32x4 s;
#pragma unroll
        for (int rr = 0; rr < 4; rr++) {
            const int ii = q4 * 4 + rr;
            s[rr] = (q4 < 2) ? BFLO(bias_lds[jt & 1][(ii * 16 + l15) * 17 + w]) : 0.f;
        }
        s = __builtin_amdgcn_mfma_f32_16x16x32_bf16(*(bf16x8*)&qf[0], *(bf16x8*)&kf[0], s, 0, 0, 0);
        s = __builtin_amdgcn_mfma_f32_16x16x32_bf16(*(bf16x8*)&qf[1], *(bf16x8*)&kf[1], s, 0, 0, 0);

        // ---- online softmax (16-lane j groups; rows i = q4*4+rr) ----
#pragma unroll
        for (int rr = 0; rr < 4; rr++) {
            float x = s[rr];
            x = fmaxf(x, __shfl_xor(x, 1));
            x = fmaxf(x, __shfl_xor(x, 2));
            x = fmaxf(x, __shfl_xor(x, 4));
            x = fmaxf(x, __shfl_xor(x, 8));
            const float mnew = fmaxf(mrun[rr], x);
            const float corr = __expf(mrun[rr] - mnew);
            mrun[rr] = mnew;
            const float p0 = __expf(s[rr] - mnew);
            float ts = p0;
            ts += __shfl_xor(ts, 1);
            ts += __shfl_xor(ts, 2);
            ts += __shfl_xor(ts, 4);
            ts += __shfl_xor(ts, 8);
            lrun[rr] = lrun[rr] * corr + ts;
#pragma unroll
            for (int dn = 0; dn < 4; dn++) acc[dn][rr] *= corr;
            pbuf[(w * 16 + q4 * 4 + rr) * 24 + l15] =
                __bfloat16_as_ushort(__float2bfloat16(p0));
        }

        // ---- P write -> A-frag read (same wave) ----
        asm volatile("s_waitcnt lgkmcnt(0)" ::: "memory");
        __builtin_amdgcn_sched_barrier(0);

        bf16x8 pfrag = (bf16x8){0, 0, 0, 0, 0, 0, 0, 0};
        if (q4 < 2) pfrag = *(bf16x8*)&pbuf[(w * 16 + l15) * 24 + q4 * 8];
#pragma unroll
        for (int dn = 0; dn < 4; dn++)
            acc[dn] = __builtin_amdgcn_mfma_f32_16x16x32_bf16(pfrag, *(bf16x8*)&vf[dn], acc[dn], 0, 0, 0);

        // ---- single per-tile barrier (bias_lds slot separation) ----
        asm volatile("s_waitcnt lgkmcnt(0)" ::: "memory");
        __builtin_amdgcn_sched_barrier(0);
        __builtin_amdgcn_s_barrier();
        __builtin_amdgcn_sched_barrier(0);
    }

    // ---- epilogue: unnormalized partials + (m,l) ----
    if (q4 < 2) {
#pragma unroll
        for (int rr = 0; rr < 4; rr++) {
            const int i = q4 * 4 + rr;
            float* crow = cp + (size_t)jh * (2048 * 512)
                        + ((size_t)(b * 1024) + i0 + i) * 512 + w * 64;
#pragma unroll
            for (int dn = 0; dn < 4; dn++)
                crow[dn * 16 + l15] = acc[dn][rr];
            if (l15 == 0) {
                const int mi = ((jh * 2 + b) * 8 + w) * 1024 + i0 + i;
                mlm[mi] = mrun[rr];
                mll[mi] = lrun[rr];
            }
        }
    }
#undef STAGE
#undef BIASCOMP
}

// ---------------------------------------------------------------------------
// Kernel 3: fused merge + out-proj. A-row = merge(cp0,cp1); out = A@W_out + b.
// ---------------------------------------------------------------------------
__global__ __launch_bounds__(256, 2) void gemm_out_fused(
    const float* __restrict__ cp, const float* __restrict__ mlm,
    const float* __restrict__ mll, const float* __restrict__ W,
    const float* __restrict__ bias, float* __restrict__ out)
{
    __shared__ float smem[64 * 68];
    float* As = smem;
    float* Bs = smem + 32 * 68;

    const int t  = threadIdx.x;
    const int m0 = blockIdx.y * 64;
    const int n0 = blockIdx.x * 64;
    const int tx = t & 15, ty = t >> 4;

    const int am = t >> 2, ak = (t & 3) * 8;
    const int bk = t >> 3, bn = (t & 7) * 8;

    const int row = m0 + am;
    const int bb  = row >> 10, ii = row & 1023;
    const float* cp0 = cp + (size_t)row * 512;
    const float* cp1 = cp + (size_t)(2048 * 512) + (size_t)row * 512;

    float acc[4][4] = {};
    float w0 = 0.f, w1 = 0.f;

    for (int k0 = 0; k0 < 512; k0 += 32) {
        if ((k0 & 63) == 0) {
            const int h   = k0 >> 6;
            const int mi0 = ((bb) * 8 + h) * 1024 + ii;
            const int mi1 = ((2 + bb) * 8 + h) * 1024 + ii;
            const float m0_ = mlm[mi0], m1_ = mlm[mi1];
            const float l0_ = mll[mi0], l1_ = mll[mi1];
            const float M   = fmaxf(m0_, m1_);
            float e0 = __expf(m0_ - M), e1 = __expf(m1_ - M);
            const float inv = 1.0f / (l0_ * e0 + l1_ * e1);
            w0 = e0 * inv; w1 = e1 * inv;
        }
        float4 c0a = *(const float4*)&cp0[k0 + ak];
        float4 c0b = *(const float4*)&cp0[k0 + ak + 4];
        float4 c1a = *(const float4*)&cp1[k0 + ak];
        float4 c1b = *(const float4*)&cp1[k0 + ak + 4];
        float4 b0 = *(const float4*)&W[(size_t)(k0 + bk) * 512 + n0 + bn];
        float4 b1 = *(const float4*)&W[(size_t)(k0 + bk) * 512 + n0 + bn + 4];
        float a0x = c0a.x * w0 + c1a.x * w1, a0y = c0a.y * w0 + c1a.y * w1;
        float a0z = c0a.z * w0 + c1a.z * w1, a0w = c0a.w * w0 + c1a.w * w1;
        float a1x = c0b.x * w0 + c1b.x * w1, a1y = c0b.y * w0 + c1b.y * w1;
        float a1z = c0b.z * w0 + c1b.z * w1, a1w = c0b.w * w0 + c1b.w * w1;
        __syncthreads();
        As[(ak + 0) * 68 + am] = a0x;
        As[(ak + 1) * 68 + am] = a0y;
        As[(ak + 2) * 68 + am] = a0z;
        As[(ak + 3) * 68 + am] = a0w;
        As[(ak + 4) * 68 + am] = a1x;
        As[(ak + 5) * 68 + am] = a1y;
        As[(ak + 6) * 68 + am] = a1z;
        As[(ak + 7) * 68 + am] = a1w;
        *(float4*)&Bs[bk * 68 + bn]     = b0;
        *(float4*)&Bs[bk * 68 + bn + 4] = b1;
        __syncthreads();
#pragma unroll
        for (int kk = 0; kk < 32; kk++) {
            float4 a4 = *(float4*)&As[kk * 68 + ty * 4];
            float4 b4 = *(float4*)&Bs[kk * 68 + tx * 4];
            float av[4] = {a4.x, a4.y, a4.z, a4.w};
            float bv[4] = {b4.x, b4.y, b4.z, b4.w};
#pragma unroll
            for (int r = 0; r < 4; r++)
#pragma unroll
                for (int c = 0; c < 4; c++) acc[r][c] += av[r] * bv[c];
        }
    }

    float4 bo = *(const float4*)&bias[n0 + tx * 4];
    float bv[4] = {bo.x, bo.y, bo.z, bo.w};
#pragma unroll
    for (int r = 0; r < 4; r++) {
        const int m = m0 + ty * 4 + r;
#pragma unroll
        for (int c = 0; c < 4; c++)
            out[(size_t)m * 512 + n0 + tx * 4 + c] = acc[r][c] + bv[c];
    }
}

// ---------------------------------------------------------------------------
extern "C" void kernel_launch(void* const* d_in, const int* in_sizes, int n_in,
                              void* d_out, int out_size, void* d_ws, size_t ws_size,
                              hipStream_t stream)
{
    const float* seq  = (const float*)d_in[0];
    const float* pair = (const float*)d_in[1];
    const float* Wqkv = (const float*)d_in[2];
    const float* Wb   = (const float*)d_in[3];
    const float* Wout = (const float*)d_in[4];
    const float* bout = (const float*)d_in[5];
    float* out = (float*)d_out;

    unsigned short* qbus  = (unsigned short*)d_ws;           // bf16 [2][8][1024][64]   2 MB
    unsigned short* kbus  = qbus + (1 << 20);                // bf16 [2][8][1024][64]   2 MB
    unsigned short* vtbus = kbus + (1 << 20);                // bf16 [2][8][64][1024]   2 MB
    unsigned short* seqb  = vtbus + (1 << 20);               // bf16 [2048][512]        2 MB
    unsigned short* wtb   = seqb + (1 << 20);                // bf16 [1536][512]        1.5 MB
    float*          cp    = (float*)(wtb + (1 << 20));       // fp32 [2][2048][512]     8 MB
    float*          mlm   = cp + (2 << 20);                  // fp32 [2][2][8][1024]  128 KB
    float*          mll   = mlm + (1 << 15);                 // fp32 [2][2][8][1024]  128 KB

    prep_kernel<<<704, 256, 0, stream>>>(seq, Wqkv, seqb, wtb);
    gemm_qkv_kernel<<<dim3(24, 32), 256, 0, stream>>>(seqb, wtb, qbus, kbus, vtbus);
    attn_kernel<<<512, 512, 0, stream>>>(pair, Wb, qbus, kbus, vtbus, cp, mlm, mll);
    gemm_out_fused<<<dim3(8, 32), 256, 0, stream>>>(cp, mlm, mll, Wout, bout, out);
}